// Round 2
// baseline (10982.598 us; speedup 1.0000x reference)
//
#include <hip/hip_runtime.h>
#include <stdint.h>

// Problem constants (bidirectionalRNN: S=256, B=32, I=H=1024, L=2)
#define SEQ   256
#define BSZ   32
#define HD    1024
#define GD    4096          // 4*H
#define KD    1024
#define MROWS (SEQ*BSZ)     // 8192
#define PBLK  128           // persistent grid: 128 blocks (<=256 CUs -> co-resident)
#define PTHR  512           // 8 waves: 4 gate-tiles x 2 K-halves

typedef unsigned short u16;
typedef __attribute__((ext_vector_type(8))) __bf16 bf8_t;
typedef __attribute__((ext_vector_type(4))) float  f4_t;

__device__ __forceinline__ u16 f2bf(float f) {
  unsigned u = __float_as_uint(f);
  u += 0x7fffu + ((u >> 16) & 1u);      // RNE
  return (u16)(u >> 16);
}
__device__ __forceinline__ float bf2f(u16 s) {
  return __uint_as_float(((unsigned)s) << 16);
}
__device__ __forceinline__ void async_copy16(const void* g, void* l) {
  __builtin_amdgcn_global_load_lds(
      (const __attribute__((address_space(1))) void*)g,
      (__attribute__((address_space(3))) void*)l, 16, 0, 0);
}
__device__ __forceinline__ float sigm(float x) { return 1.0f / (1.0f + __expf(-x)); }
__device__ __forceinline__ float tanh_f(float x) {
  float e = __expf(-2.0f * x);          // inf-safe: x<<0 -> e=inf -> -1
  return 2.0f / (1.0f + e) - 1.0f;
}

// ---------------- fp32 -> bf16 conversion (x4 vectorized) ----------------
__global__ void cvt_f32_bf16(const float* __restrict__ src, u16* __restrict__ dst, int n4) {
  int i = blockIdx.x * blockDim.x + threadIdx.x;
  if (i >= n4) return;
  float4 v = ((const float4*)src)[i];
  ushort4 o;
  o.x = f2bf(v.x); o.y = f2bf(v.y); o.z = f2bf(v.z); o.w = f2bf(v.w);
  ((ushort4*)dst)[i] = o;
}

// ------- w_hh reorder+convert: gate-interleaved block-owned row layout ----
// src [2L][4096][1024] f32 (one dir). dst row' for (layer,g,j):
//   block jblk=j>>4 owns rows ((d*2+layer)*64 + jblk)*64 + g*16 + (j&15)
__global__ void reorder_whh(const float* __restrict__ src, u16* __restrict__ dst, int d) {
  int r = blockIdx.x;                 // 0..8191
  int layer = r >> 12, row = r & 4095;
  int g = row >> 10, j = row & 1023;
  int jblk = j >> 4, jl = j & 15;
  size_t drow = ((size_t)(d * 2 + layer) * 64 + jblk) * 64 + g * 16 + jl;
  float4 v = ((const float4*)(src + (size_t)r * KD))[threadIdx.x];
  ushort4 o;
  o.x = f2bf(v.x); o.y = f2bf(v.y); o.z = f2bf(v.z); o.w = f2bf(v.w);
  ((ushort4*)(dst + drow * KD))[threadIdx.x] = o;
}

// ---------------- bf16 GEMM: C[M,N] = A[M,K] @ B[N,K]^T, C in bf16 -------
// m97 structure: 128x128 tile, 4 waves, 4x4 16x16x32 MFMA tiles per wave,
// BK=32, global_load_lds width=16 staging. (unchanged from round 1 — passed)
__global__ __launch_bounds__(256) void gemm_bt(
    const u16* __restrict__ A, const u16* __restrict__ B, u16* __restrict__ C,
    int M, int N, int K)
{
  __shared__ u16 lA[128 * 32];
  __shared__ u16 lB[128 * 32];
  const int tid  = threadIdx.x;
  const int wave = tid >> 6, lane = tid & 63;
  const int wr = (wave >> 1) * 64, wc = (wave & 1) * 64;
  const int m0 = blockIdx.x * 128, n0 = blockIdx.y * 128;

  f4_t acc[4][4] = {};

  const int r0 = tid >> 2,          kp0 = (tid & 3) * 8;
  const int r1 = (tid + 256) >> 2,  kp1 = (tid & 3) * 8;
  const u16* gA0 = A + (size_t)(m0 + r0) * K + kp0;
  const u16* gA1 = A + (size_t)(m0 + r1) * K + kp1;
  const u16* gB0 = B + (size_t)(n0 + r0) * K + kp0;
  const u16* gB1 = B + (size_t)(n0 + r1) * K + kp1;
  u16* lA0 = lA + wave * 512;          u16* lA1 = lA + 2048 + wave * 512;
  u16* lB0 = lB + wave * 512;          u16* lB1 = lB + 2048 + wave * 512;

  const int fr = lane & 15, fk = (lane >> 4) * 8;

  for (int k0 = 0; k0 < K; k0 += 32) {
    async_copy16(gA0 + k0, lA0);
    async_copy16(gA1 + k0, lA1);
    async_copy16(gB0 + k0, lB0);
    async_copy16(gB1 + k0, lB1);
    __syncthreads();
    bf8_t af[4], bf[4];
    #pragma unroll
    for (int i = 0; i < 4; i++) af[i] = *(const bf8_t*)&lA[(wr + i * 16 + fr) * 32 + fk];
    #pragma unroll
    for (int i = 0; i < 4; i++) bf[i] = *(const bf8_t*)&lB[(wc + i * 16 + fr) * 32 + fk];
    #pragma unroll
    for (int mi = 0; mi < 4; mi++)
      #pragma unroll
      for (int ni = 0; ni < 4; ni++)
        acc[mi][ni] = __builtin_amdgcn_mfma_f32_16x16x32_bf16(af[mi], bf[ni], acc[mi][ni], 0, 0, 0);
    __syncthreads();
  }
  const int er = (lane >> 4) * 4, ec = lane & 15;
  #pragma unroll
  for (int mi = 0; mi < 4; mi++)
    #pragma unroll
    for (int ni = 0; ni < 4; ni++)
      #pragma unroll
      for (int r = 0; r < 4; r++) {
        int m = m0 + wr + mi * 16 + er + r;
        int n = n0 + wc + ni * 16 + ec;
        C[(size_t)m * N + n] = f2bf(acc[mi][ni][r]);
      }
}

// -------- persistent weight-stationary recurrence (one launch per layer) --
// 128 blocks x 512 thr. Block: dir d = bid&1, jblk = bid>>1 -> owns j in
// [jblk*16, jblk*16+16), all 4 gates (64 reordered weight rows). Wave w:
// gate-tile mt = w>>1 (== gate), K-half kh = w&1. Weights live in 64 VGPRs
// per lane for the whole kernel. One device-scope grid barrier per step.
__global__ __launch_bounds__(PTHR) void lstm_persist(
    const u16* __restrict__ whh_r,  // [2d][2l][64 jblk][64 rows][1024] bf16
    const u16* __restrict__ xg,     // [2d][8192][4096] bf16
    u16*       __restrict__ hst,    // [2buf][2d][32][1024] bf16 (zeroed)
    u16*       __restrict__ h0out,  // [2d][8192][1024] bf16
    float*     __restrict__ dout,
    unsigned*  __restrict__ cnt,    // zeroed barrier counter
    int layer)
{
  const int tid = threadIdx.x;
  const int lane = tid & 63;
  const int mt = (tid >> 6) >> 1, kh = (tid >> 6) & 1;
  const int d = blockIdx.x & 1, jblk = blockIdx.x >> 1;
  const int j0 = jblk * 16;
  const int fr = lane & 15, quad = lane >> 4;

  // one-time weight fragment load: B[n=fr (row mt*16+fr)][k in K-half kh]
  bf8_t wreg[16];
  {
    const u16* wp = whh_r
        + ((size_t)(((d * 2 + layer) * 64 + jblk) * 64 + mt * 16 + fr)) * KD
        + kh * 512 + quad * 8;
    #pragma unroll
    for (int ks = 0; ks < 16; ks++) wreg[ks] = *(const bf8_t*)(wp + ks * 32);
  }

  __shared__ float lAcc[4][2][32][16];   // [gate][khalf][batch][jl] partials
  const int b_ = tid >> 4, jl = tid & 15;
  float creg = 0.0f;                      // cell state lives in a register

  for (int t = 0; t < SEQ; t++) {
    const int tt = d ? (SEQ - 1 - t) : t;
    const int rbuf = t & 1, wbuf = rbuf ^ 1;
    const u16* hA = hst + (size_t)(rbuf * 2 + d) * BSZ * HD + kh * 512 + quad * 8;

    f4_t acc0 = {}, acc1 = {};
    #pragma unroll 8
    for (int ks = 0; ks < 16; ks++) {
      bf8_t a0 = *(const bf8_t*)(hA + (size_t)fr * HD + ks * 32);        // b 0-15
      bf8_t a1 = *(const bf8_t*)(hA + (size_t)(fr + 16) * HD + ks * 32); // b 16-31
      acc0 = __builtin_amdgcn_mfma_f32_16x16x32_bf16(a0, wreg[ks], acc0, 0, 0, 0);
      acc1 = __builtin_amdgcn_mfma_f32_16x16x32_bf16(a1, wreg[ks], acc1, 0, 0, 0);
    }
    // D layout: col=lane&15 (weight row), row=(lane>>4)*4+r (batch)
    #pragma unroll
    for (int r = 0; r < 4; r++) {
      lAcc[mt][kh][quad * 4 + r][fr]      = acc0[r];
      lAcc[mt][kh][16 + quad * 4 + r][fr] = acc1[r];
    }
    __syncthreads();

    // cell update: thread -> (batch b_, j = j0+jl)
    {
      const u16* xgp = xg + ((size_t)d * MROWS + (size_t)tt * BSZ + b_) * GD + j0 + jl;
      float v0 = lAcc[0][0][b_][jl] + lAcc[0][1][b_][jl] + bf2f(xgp[0]);
      float v1 = lAcc[1][0][b_][jl] + lAcc[1][1][b_][jl] + bf2f(xgp[1024]);
      float v2 = lAcc[2][0][b_][jl] + lAcc[2][1][b_][jl] + bf2f(xgp[2048]);
      float v3 = lAcc[3][0][b_][jl] + lAcc[3][1][b_][jl] + bf2f(xgp[3072]);
      float iv = sigm(v0), fv = sigm(v1), gv = tanh_f(v2), ov = sigm(v3);
      float cn = fv * creg + iv * gv; creg = cn;
      float hn = ov * tanh_f(cn);
      hst[((size_t)(wbuf * 2 + d) * BSZ + b_) * HD + j0 + jl] = f2bf(hn);
      if (layer == 0)
        h0out[((size_t)d * MROWS + (size_t)tt * BSZ + b_) * HD + j0 + jl] = f2bf(hn);
      else
        dout[((size_t)tt * BSZ + b_) * (2 * HD) + (size_t)d * HD + j0 + jl] = hn;
      // h_last/c_last: fwd at final step; bwd at its FIRST step (torch quirk)
      if ((d == 0 && t == SEQ - 1) || (d == 1 && t == 0)) {
        size_t hoff = (size_t)MROWS * 2 * HD + ((size_t)layer * BSZ + b_) * (2 * HD)
                    + (size_t)d * HD + j0 + jl;
        dout[hoff] = hn;
        dout[hoff + (size_t)2 * BSZ * 2 * HD] = cn;
      }
    }

    // grid barrier: release my writes, arrive, spin, acquire
    __syncthreads();
    if (tid == 0) {
      __threadfence();                              // buffer_wbl2: push h to device scope
      atomicAdd(cnt, 1u);
      const unsigned goal = (unsigned)PBLK * (unsigned)(t + 1);
      int spins = 0;
      while (__hip_atomic_load(cnt, __ATOMIC_RELAXED, __HIP_MEMORY_SCOPE_AGENT) < goal) {
        __builtin_amdgcn_s_sleep(1);
        if (++spins > (1 << 26)) break;             // safety escape (never under co-residency)
      }
      __threadfence();                              // buffer_inv: drop stale h from caches
    }
    __syncthreads();
  }
}

// -------------------------------------------------------------------------
extern "C" void kernel_launch(void* const* d_in, const int* in_sizes, int n_in,
                              void* d_out, int out_size, void* d_ws, size_t ws_size,
                              hipStream_t stream) {
  const float* x    = (const float*)d_in[0];
  const float* wihf = (const float*)d_in[1];
  const float* whhf = (const float*)d_in[2];
  const float* wihb = (const float*)d_in[3];
  const float* whhb = (const float*)d_in[4];
  float* out = (float*)d_out;

  const size_t NE = (size_t)MROWS * KD;   // 8.4M elems per [2,4096,1024] tensor
  char* ws = (char*)d_ws;
  u16*   xbf  = (u16*)ws;                                   // 16 MB
  u16*   wih  = (u16*)(ws + NE * 2);                        // [2d][2l][4096][1024], 32 MB
  u16*   whhr = wih + 2 * NE;                               // reordered, 32 MB
  u16*   xg   = whhr + 2 * NE;                              // [2d][8192][4096], 128 MB
  u16*   h0   = xg + (size_t)2 * MROWS * GD;                // [2d][8192][1024], 32 MB
  u16*   hst  = h0 + (size_t)2 * MROWS * HD;                // [2buf][2d][32][1024], 256 KB
  unsigned* cnt = (unsigned*)(hst + (size_t)2 * 2 * BSZ * HD);

  // 1) convert / reorder inputs to bf16
  const int n4 = (int)(NE / 4);
  const int cg = n4 / 256;
  cvt_f32_bf16<<<cg, 256, 0, stream>>>(x,    xbf,      n4);
  cvt_f32_bf16<<<cg, 256, 0, stream>>>(wihf, wih,      n4);
  cvt_f32_bf16<<<cg, 256, 0, stream>>>(wihb, wih + NE, n4);
  reorder_whh<<<2 * GD, 256, 0, stream>>>(whhf, whhr, 0);
  reorder_whh<<<2 * GD, 256, 0, stream>>>(whhb, whhr, 1);

  hipMemsetAsync(cnt, 0, 2 * sizeof(unsigned), stream);
  const size_t hstBytes = (size_t)2 * 2 * BSZ * HD * 2;
  hipMemsetAsync(hst, 0, hstBytes, stream);

  dim3 gg(MROWS / 128, GD / 128);   // 64 x 32

  // 2) layer-0 input projections + recurrence
  for (int d = 0; d < 2; d++)
    gemm_bt<<<gg, 256, 0, stream>>>(xbf, wih + (size_t)(d * 2) * GD * KD,
                                    xg + (size_t)d * MROWS * GD, MROWS, GD, KD);
  lstm_persist<<<PBLK, PTHR, 0, stream>>>(whhr, xg, hst, h0, out, cnt + 0, 0);

  // 3) layer-1 input projections + recurrence
  for (int d = 0; d < 2; d++)
    gemm_bt<<<gg, 256, 0, stream>>>(h0 + (size_t)d * MROWS * HD,
                                    wih + (size_t)(d * 2 + 1) * GD * KD,
                                    xg + (size_t)d * MROWS * GD, MROWS, GD, KD);
  hipMemsetAsync(hst, 0, hstBytes, stream);
  lstm_persist<<<PBLK, PTHR, 0, stream>>>(whhr, xg, hst, h0, out, cnt + 1, 1);
}

// Round 3
// 3275.833 us; speedup vs baseline: 3.3526x; 3.3526x over previous
//
#include <hip/hip_runtime.h>
#include <stdint.h>

// Problem constants (bidirectionalRNN: S=256, B=32, I=H=1024, L=2)
#define SEQ   256
#define BSZ   32
#define HD    1024
#define GD    4096          // 4*H
#define KD    1024
#define MROWS (SEQ*BSZ)     // 8192
#define PBLK  128           // persistent grid: 128 blocks, 1/CU guaranteed co-resident
#define PTHR  512           // 8 waves: 4 gate-tiles x 2 K-halves

typedef unsigned short u16;
typedef __attribute__((ext_vector_type(8))) __bf16 bf8_t;
typedef __attribute__((ext_vector_type(4))) float  f4_t;
typedef __attribute__((ext_vector_type(4))) unsigned int u4_t;

__device__ __forceinline__ u16 f2bf(float f) {
  unsigned u = __float_as_uint(f);
  u += 0x7fffu + ((u >> 16) & 1u);      // RNE
  return (u16)(u >> 16);
}
__device__ __forceinline__ float bf2f(u16 s) {
  return __uint_as_float(((unsigned)s) << 16);
}
__device__ __forceinline__ void async_copy16(const void* g, void* l) {
  __builtin_amdgcn_global_load_lds(
      (const __attribute__((address_space(1))) void*)g,
      (__attribute__((address_space(3))) void*)l, 16, 0, 0);
}
__device__ __forceinline__ float sigm(float x) { return 1.0f / (1.0f + __expf(-x)); }
__device__ __forceinline__ float tanh_f(float x) {
  float e = __expf(-2.0f * x);          // inf-safe: x<<0 -> e=inf -> -1
  return 2.0f / (1.0f + e) - 1.0f;
}

// ---------------- fp32 -> bf16 conversion (x4 vectorized) ----------------
__global__ void cvt_f32_bf16(const float* __restrict__ src, u16* __restrict__ dst, int n4) {
  int i = blockIdx.x * blockDim.x + threadIdx.x;
  if (i >= n4) return;
  float4 v = ((const float4*)src)[i];
  ushort4 o;
  o.x = f2bf(v.x); o.y = f2bf(v.y); o.z = f2bf(v.z); o.w = f2bf(v.w);
  ((ushort4*)dst)[i] = o;
}

// ------- w_hh reorder+convert: gate-interleaved block-owned row layout ----
__global__ void reorder_whh(const float* __restrict__ src, u16* __restrict__ dst, int d) {
  int r = blockIdx.x;                 // 0..8191
  int layer = r >> 12, row = r & 4095;
  int g = row >> 10, j = row & 1023;
  int jblk = j >> 4, jl = j & 15;
  size_t drow = ((size_t)(d * 2 + layer) * 64 + jblk) * 64 + g * 16 + jl;
  float4 v = ((const float4*)(src + (size_t)r * KD))[threadIdx.x];
  ushort4 o;
  o.x = f2bf(v.x); o.y = f2bf(v.y); o.z = f2bf(v.z); o.w = f2bf(v.w);
  ((ushort4*)(dst + drow * KD))[threadIdx.x] = o;
}

// ---------------- bf16 GEMM: C[M,N] = A[M,K] @ B[N,K]^T, C in bf16 -------
__global__ __launch_bounds__(256) void gemm_bt(
    const u16* __restrict__ A, const u16* __restrict__ B, u16* __restrict__ C,
    int M, int N, int K)
{
  __shared__ u16 lA[128 * 32];
  __shared__ u16 lB[128 * 32];
  const int tid  = threadIdx.x;
  const int wave = tid >> 6, lane = tid & 63;
  const int wr = (wave >> 1) * 64, wc = (wave & 1) * 64;
  const int m0 = blockIdx.x * 128, n0 = blockIdx.y * 128;

  f4_t acc[4][4] = {};

  const int r0 = tid >> 2,          kp0 = (tid & 3) * 8;
  const int r1 = (tid + 256) >> 2,  kp1 = (tid & 3) * 8;
  const u16* gA0 = A + (size_t)(m0 + r0) * K + kp0;
  const u16* gA1 = A + (size_t)(m0 + r1) * K + kp1;
  const u16* gB0 = B + (size_t)(n0 + r0) * K + kp0;
  const u16* gB1 = B + (size_t)(n0 + r1) * K + kp1;
  u16* lA0 = lA + wave * 512;          u16* lA1 = lA + 2048 + wave * 512;
  u16* lB0 = lB + wave * 512;          u16* lB1 = lB + 2048 + wave * 512;

  const int fr = lane & 15, fk = (lane >> 4) * 8;

  for (int k0 = 0; k0 < K; k0 += 32) {
    async_copy16(gA0 + k0, lA0);
    async_copy16(gA1 + k0, lA1);
    async_copy16(gB0 + k0, lB0);
    async_copy16(gB1 + k0, lB1);
    __syncthreads();
    bf8_t af[4], bf[4];
    #pragma unroll
    for (int i = 0; i < 4; i++) af[i] = *(const bf8_t*)&lA[(wr + i * 16 + fr) * 32 + fk];
    #pragma unroll
    for (int i = 0; i < 4; i++) bf[i] = *(const bf8_t*)&lB[(wc + i * 16 + fr) * 32 + fk];
    #pragma unroll
    for (int mi = 0; mi < 4; mi++)
      #pragma unroll
      for (int ni = 0; ni < 4; ni++)
        acc[mi][ni] = __builtin_amdgcn_mfma_f32_16x16x32_bf16(af[mi], bf[ni], acc[mi][ni], 0, 0, 0);
    __syncthreads();
  }
  const int er = (lane >> 4) * 4, ec = lane & 15;
  #pragma unroll
  for (int mi = 0; mi < 4; mi++)
    #pragma unroll
    for (int ni = 0; ni < 4; ni++)
      #pragma unroll
      for (int r = 0; r < 4; r++) {
        int m = m0 + wr + mi * 16 + er + r;
        int n = n0 + wc + ni * 16 + ec;
        C[(size_t)m * N + n] = f2bf(acc[mi][ni][r]);
      }
}

// -------- persistent weight-stationary recurrence (one launch per layer) --
// 128 blocks x 512 thr. Block: dir d = bid&1, jblk = bid>>1 -> owns 16 h-dims,
// all 4 gates. Wave w: gate-tile mt = w>>1, K-half kh = w&1. Weights pinned in
// 64 VGPRs/lane via asm. h exchange: relaxed AGENT-scope atomics (sc1 — per-
// access device coherence, NO cache-wide fences). Grid barrier: 2-level
// relaxed agent atomic counters; store->arrive ordering via s_waitcnt vmcnt(0).
__global__ __launch_bounds__(PTHR) void lstm_persist(
    const u16* __restrict__ whh_r,  // [2d][2l][64 jblk][64 rows][1024] bf16
    const u16* __restrict__ xg,     // [2d][8192][4096] bf16
    u16*       __restrict__ hst,    // [2buf][2d][32][1024] bf16 (zeroed)
    u16*       __restrict__ h0out,  // [2d][8192][1024] bf16
    float*     __restrict__ dout,
    unsigned*  __restrict__ cnt,    // zeroed: [0]=root, [16*(1+s)]=sub s
    int layer)
{
  const int tid = threadIdx.x;
  const int lane = tid & 63;
  const int mt = (tid >> 6) >> 1, kh = (tid >> 6) & 1;
  const int d = blockIdx.x & 1, jblk = blockIdx.x >> 1;
  const int j0 = jblk * 16;
  const int fr = lane & 15, quad = lane >> 4;

  // 64 KB LDS: h staging [32 rows][512 dwords], XOR-swizzled in 16B chunks
  // (physchunk = chunk ^ (row&7)) -> 2-way-max bank aliasing (free, m136).
  // After the MFMA phase the first 16 KB is reused as the gate-partial
  // exchange buffer lAcc[4 gates][2 kh][32 b][16 jl] (barrier-separated).
  __shared__ __align__(16) uint32_t lH[32 * 512];
  float* lAcc = (float*)lH;

  // ---- one-time weight fragment load, pinned in VGPRs ----
  u4_t wreg[16];
  {
    const u16* wp = whh_r
        + ((size_t)(((d * 2 + layer) * 64 + jblk) * 64 + mt * 16 + fr)) * KD
        + kh * 512 + quad * 8;
    #pragma unroll
    for (int ks = 0; ks < 16; ks++) wreg[ks] = *(const u4_t*)(wp + ks * 32);
    #pragma unroll
    for (int ks = 0; ks < 16; ks++) asm volatile("" : "+v"(wreg[ks]));  // stop load sinking
  }

  const int b_ = tid >> 3, jp = tid & 7;   // cell phase: tid<256 -> (batch, j-pair)
  float cr0 = 0.0f, cr1 = 0.0f;            // two cell states per active thread

  for (int t = 0; t < SEQ; t++) {
    const int tt = d ? (SEQ - 1 - t) : t;
    const int rbuf = t & 1, wbuf = rbuf ^ 1;

    // ---- stage h(rbuf) [32][1024]bf16 into LDS via device-coherent loads ----
    unsigned long long* hsrc = (unsigned long long*)(hst + (size_t)(rbuf * 2 + d) * BSZ * HD);
    unsigned long long hv[16];
    #pragma unroll
    for (int g = 0; g < 16; g++)
      hv[g] = __hip_atomic_load(hsrc + g * 512 + tid, __ATOMIC_RELAXED, __HIP_MEMORY_SCOPE_AGENT);

    uint32_t xv[4];                        // xg prefetch (regular loads, L2-hot)
    if (tid < 256) {
      const uint32_t* xgp = (const uint32_t*)(xg
          + ((size_t)d * MROWS + (size_t)tt * BSZ + b_) * GD + j0) + jp;
      #pragma unroll
      for (int g = 0; g < 4; g++) xv[g] = xgp[g * 512];
    }

    #pragma unroll
    for (int g = 0; g < 16; g++) {
      int qi = g * 512 + tid;              // qword index in [32][256]
      int row = qi >> 8, c8 = qi & 255;
      int chunk = (c8 >> 1) ^ (row & 7);
      *(unsigned long long*)&lH[row * 512 + chunk * 4 + (c8 & 1) * 2] = hv[g];
    }
    __syncthreads();

    // ---- recurrent MFMA: gates[b][16j] for gate mt, K-half kh ----
    f4_t acc0 = {}, acc1 = {};
    #pragma unroll
    for (int ks = 0; ks < 16; ks++) {
      int cbase = ((kh * 64 + ks * 4 + quad) ^ (fr & 7)) << 2;   // (fr+16)&7 == fr&7
      bf8_t a0 = *(const bf8_t*)&lH[fr * 512 + cbase];           // batches 0-15
      bf8_t a1 = *(const bf8_t*)&lH[(fr + 16) * 512 + cbase];    // batches 16-31
      bf8_t wb = __builtin_bit_cast(bf8_t, wreg[ks]);
      acc0 = __builtin_amdgcn_mfma_f32_16x16x32_bf16(a0, wb, acc0, 0, 0, 0);
      acc1 = __builtin_amdgcn_mfma_f32_16x16x32_bf16(a1, wb, acc1, 0, 0, 0);
    }
    __syncthreads();                       // all frag reads done: lAcc may overlay lH

    // D layout: col=lane&15 (j), row=(lane>>4)*4+r (batch)
    #pragma unroll
    for (int r = 0; r < 4; r++) {
      lAcc[((mt * 2 + kh) * 32 + quad * 4 + r) * 16 + fr]      = acc0[r];
      lAcc[((mt * 2 + kh) * 32 + 16 + quad * 4 + r) * 16 + fr] = acc1[r];
    }
    __syncthreads();

    // ---- cell update: 256 threads x 2 adjacent j each ----
    if (tid < 256) {
      float vg0[4], vg1[4];
      #pragma unroll
      for (int g = 0; g < 4; g++) {
        float2 p0 = *(const float2*)&lAcc[((g * 2 + 0) * 32 + b_) * 16 + 2 * jp];
        float2 p1 = *(const float2*)&lAcc[((g * 2 + 1) * 32 + b_) * 16 + 2 * jp];
        vg0[g] = p0.x + p1.x + bf2f((u16)(xv[g] & 0xffffu));
        vg1[g] = p0.y + p1.y + bf2f((u16)(xv[g] >> 16));
      }
      float i0 = sigm(vg0[0]), f0 = sigm(vg0[1]), g0 = tanh_f(vg0[2]), o0 = sigm(vg0[3]);
      float i1 = sigm(vg1[0]), f1 = sigm(vg1[1]), g1 = tanh_f(vg1[2]), o1 = sigm(vg1[3]);
      cr0 = f0 * cr0 + i0 * g0;
      cr1 = f1 * cr1 + i1 * g1;
      float hn0 = o0 * tanh_f(cr0), hn1 = o1 * tanh_f(cr1);
      uint32_t hnp = ((uint32_t)f2bf(hn1) << 16) | (uint32_t)f2bf(hn0);

      size_t hq = (((size_t)(wbuf * 2 + d) * BSZ + b_) * HD + j0 + 2 * jp) >> 1;
      __hip_atomic_store((uint32_t*)hst + hq, hnp, __ATOMIC_RELAXED, __HIP_MEMORY_SCOPE_AGENT);

      if (layer == 0) {
        *(uint32_t*)&h0out[((size_t)d * MROWS + (size_t)tt * BSZ + b_) * HD + j0 + 2 * jp] = hnp;
      } else {
        float2 o2 = make_float2(hn0, hn1);
        *(float2*)&dout[((size_t)tt * BSZ + b_) * (2 * HD) + (size_t)d * HD + j0 + 2 * jp] = o2;
      }
      // h_last/c_last: fwd at final step; bwd at its FIRST step (torch quirk)
      if ((d == 0 && t == SEQ - 1) || (d == 1 && t == 0)) {
        size_t hoff = (size_t)MROWS * 2 * HD + ((size_t)layer * BSZ + b_) * (2 * HD)
                    + (size_t)d * HD + j0 + 2 * jp;
        dout[hoff] = hn0;  dout[hoff + 1] = hn1;
        dout[hoff + (size_t)2 * BSZ * 2 * HD]     = cr0;
        dout[hoff + (size_t)2 * BSZ * 2 * HD + 1] = cr1;
      }
    }

    // ---- grid barrier (no cache-wide fences) ----
    asm volatile("s_waitcnt vmcnt(0)" ::: "memory");  // sc1 stores globally visible
    __syncthreads();
    if (tid == 0) {
      const unsigned sub = (unsigned)(blockIdx.x & 7);
      unsigned old = __hip_atomic_fetch_add(&cnt[16 * (1 + sub)], 1u,
                                            __ATOMIC_RELAXED, __HIP_MEMORY_SCOPE_AGENT);
      if (old + 1u == (unsigned)(PBLK / 8) * (unsigned)(t + 1))
        __hip_atomic_fetch_add(&cnt[0], 1u, __ATOMIC_RELAXED, __HIP_MEMORY_SCOPE_AGENT);
      const unsigned goal = 8u * (unsigned)(t + 1);
      long spins = 0;
      while (__hip_atomic_load(&cnt[0], __ATOMIC_RELAXED, __HIP_MEMORY_SCOPE_AGENT) < goal) {
        if (++spins > (1L << 27)) break;   // safety escape (never under co-residency)
      }
    }
    __syncthreads();
    asm volatile("" ::: "memory");         // keep next step's loads below the barrier
  }
}

// -------------------------------------------------------------------------
extern "C" void kernel_launch(void* const* d_in, const int* in_sizes, int n_in,
                              void* d_out, int out_size, void* d_ws, size_t ws_size,
                              hipStream_t stream) {
  const float* x    = (const float*)d_in[0];
  const float* wihf = (const float*)d_in[1];
  const float* whhf = (const float*)d_in[2];
  const float* wihb = (const float*)d_in[3];
  const float* whhb = (const float*)d_in[4];
  float* out = (float*)d_out;

  const size_t NE = (size_t)MROWS * KD;   // 8.4M elems per [2,4096,1024] tensor
  char* ws = (char*)d_ws;
  u16*   xbf  = (u16*)ws;                                   // 16 MB
  u16*   wih  = (u16*)(ws + NE * 2);                        // 32 MB
  u16*   whhr = wih + 2 * NE;                               // reordered, 32 MB
  u16*   xg   = whhr + 2 * NE;                              // 128 MB
  u16*   h0   = xg + (size_t)2 * MROWS * GD;                // 32 MB
  u16*   hst  = h0 + (size_t)2 * MROWS * HD;                // 256 KB
  unsigned* cnt = (unsigned*)(hst + (size_t)2 * 2 * BSZ * HD);  // 2 x 1 KB

  const int n4 = (int)(NE / 4);
  const int cg = n4 / 256;
  cvt_f32_bf16<<<cg, 256, 0, stream>>>(x,    xbf,      n4);
  cvt_f32_bf16<<<cg, 256, 0, stream>>>(wihf, wih,      n4);
  cvt_f32_bf16<<<cg, 256, 0, stream>>>(wihb, wih + NE, n4);
  reorder_whh<<<2 * GD, 256, 0, stream>>>(whhf, whhr, 0);
  reorder_whh<<<2 * GD, 256, 0, stream>>>(whhb, whhr, 1);

  hipMemsetAsync(cnt, 0, 2048, stream);
  const size_t hstBytes = (size_t)2 * 2 * BSZ * HD * 2;
  hipMemsetAsync(hst, 0, hstBytes, stream);

  dim3 gg(MROWS / 128, GD / 128);   // 64 x 32

  for (int d = 0; d < 2; d++)
    gemm_bt<<<gg, 256, 0, stream>>>(xbf, wih + (size_t)(d * 2) * GD * KD,
                                    xg + (size_t)d * MROWS * GD, MROWS, GD, KD);
  lstm_persist<<<PBLK, PTHR, 0, stream>>>(whhr, xg, hst, h0, out, cnt, 0);

  for (int d = 0; d < 2; d++)
    gemm_bt<<<gg, 256, 0, stream>>>(h0 + (size_t)d * MROWS * HD,
                                    wih + (size_t)(d * 2 + 1) * GD * KD,
                                    xg + (size_t)d * MROWS * GD, MROWS, GD, KD);
  hipMemsetAsync(hst, 0, hstBytes, stream);
  lstm_persist<<<PBLK, PTHR, 0, stream>>>(whhr, xg, hst, h0, out, cnt + 256, 1);
}

// Round 4
// 2975.427 us; speedup vs baseline: 3.6911x; 1.1010x over previous
//
#include <hip/hip_runtime.h>
#include <stdint.h>

// Problem constants (bidirectionalRNN: S=256, B=32, I=H=1024, L=2)
#define SEQ   256
#define BSZ   32
#define HD    1024
#define GD    4096          // 4*H
#define KD    1024
#define MROWS (SEQ*BSZ)     // 8192
#define PBLK  128           // persistent grid: 128 blocks, co-resident (<=256 CUs)
#define PTHR  512           // 8 waves: 4 gate-tiles x 2 K-halves

typedef unsigned short u16;
typedef __attribute__((ext_vector_type(8))) __bf16 bf8_t;
typedef __attribute__((ext_vector_type(4))) float  f4_t;
typedef __attribute__((ext_vector_type(4))) unsigned int u4_t;

__device__ __forceinline__ u16 f2bf(float f) {
  unsigned u = __float_as_uint(f);
  u += 0x7fffu + ((u >> 16) & 1u);      // RNE
  return (u16)(u >> 16);
}
__device__ __forceinline__ float bf2f(u16 s) {
  return __uint_as_float(((unsigned)s) << 16);
}
__device__ __forceinline__ void async_copy16(const void* g, void* l) {
  __builtin_amdgcn_global_load_lds(
      (const __attribute__((address_space(1))) void*)g,
      (__attribute__((address_space(3))) void*)l, 16, 0, 0);
}
__device__ __forceinline__ float sigm(float x) { return 1.0f / (1.0f + __expf(-x)); }
__device__ __forceinline__ float tanh_f(float x) {
  float e = __expf(-2.0f * x);          // inf-safe: x<<0 -> e=inf -> -1
  return 2.0f / (1.0f + e) - 1.0f;
}

// ---------------- fp32 -> bf16 conversion (x4 vectorized) ----------------
__global__ void cvt_f32_bf16(const float* __restrict__ src, u16* __restrict__ dst, int n4) {
  int i = blockIdx.x * blockDim.x + threadIdx.x;
  if (i >= n4) return;
  float4 v = ((const float4*)src)[i];
  ushort4 o;
  o.x = f2bf(v.x); o.y = f2bf(v.y); o.z = f2bf(v.z); o.w = f2bf(v.w);
  ((ushort4*)dst)[i] = o;
}

// ------- w_hh reorder+convert: gate-interleaved block-owned row layout ----
__global__ void reorder_whh(const float* __restrict__ src, u16* __restrict__ dst, int d) {
  int r = blockIdx.x;                 // 0..8191
  int layer = r >> 12, row = r & 4095;
  int g = row >> 10, j = row & 1023;
  int jblk = j >> 4, jl = j & 15;
  size_t drow = ((size_t)(d * 2 + layer) * 64 + jblk) * 64 + g * 16 + jl;
  float4 v = ((const float4*)(src + (size_t)r * KD))[threadIdx.x];
  ushort4 o;
  o.x = f2bf(v.x); o.y = f2bf(v.y); o.z = f2bf(v.z); o.w = f2bf(v.w);
  ((ushort4*)(dst + drow * KD))[threadIdx.x] = o;
}

// ---------------- bf16 GEMM: C[M,N] = A[M,K] @ B[N,K]^T, C in bf16 -------
__global__ __launch_bounds__(256) void gemm_bt(
    const u16* __restrict__ A, const u16* __restrict__ B, u16* __restrict__ C,
    int M, int N, int K)
{
  __shared__ u16 lA[128 * 32];
  __shared__ u16 lB[128 * 32];
  const int tid  = threadIdx.x;
  const int wave = tid >> 6, lane = tid & 63;
  const int wr = (wave >> 1) * 64, wc = (wave & 1) * 64;
  const int m0 = blockIdx.x * 128, n0 = blockIdx.y * 128;

  f4_t acc[4][4] = {};

  const int r0 = tid >> 2,          kp0 = (tid & 3) * 8;
  const int r1 = (tid + 256) >> 2,  kp1 = (tid & 3) * 8;
  const u16* gA0 = A + (size_t)(m0 + r0) * K + kp0;
  const u16* gA1 = A + (size_t)(m0 + r1) * K + kp1;
  const u16* gB0 = B + (size_t)(n0 + r0) * K + kp0;
  const u16* gB1 = B + (size_t)(n0 + r1) * K + kp1;
  u16* lA0 = lA + wave * 512;          u16* lA1 = lA + 2048 + wave * 512;
  u16* lB0 = lB + wave * 512;          u16* lB1 = lB + 2048 + wave * 512;

  const int fr = lane & 15, fk = (lane >> 4) * 8;

  for (int k0 = 0; k0 < K; k0 += 32) {
    async_copy16(gA0 + k0, lA0);
    async_copy16(gA1 + k0, lA1);
    async_copy16(gB0 + k0, lB0);
    async_copy16(gB1 + k0, lB1);
    __syncthreads();
    bf8_t af[4], bf[4];
    #pragma unroll
    for (int i = 0; i < 4; i++) af[i] = *(const bf8_t*)&lA[(wr + i * 16 + fr) * 32 + fk];
    #pragma unroll
    for (int i = 0; i < 4; i++) bf[i] = *(const bf8_t*)&lB[(wc + i * 16 + fr) * 32 + fk];
    #pragma unroll
    for (int mi = 0; mi < 4; mi++)
      #pragma unroll
      for (int ni = 0; ni < 4; ni++)
        acc[mi][ni] = __builtin_amdgcn_mfma_f32_16x16x32_bf16(af[mi], bf[ni], acc[mi][ni], 0, 0, 0);
    __syncthreads();
  }
  const int er = (lane >> 4) * 4, ec = lane & 15;
  #pragma unroll
  for (int mi = 0; mi < 4; mi++)
    #pragma unroll
    for (int ni = 0; ni < 4; ni++)
      #pragma unroll
      for (int r = 0; r < 4; r++) {
        int m = m0 + wr + mi * 16 + er + r;
        int n = n0 + wc + ni * 16 + ec;
        C[(size_t)m * N + n] = f2bf(acc[mi][ni][r]);
      }
}

// -------- persistent weight-stationary recurrence (one launch per layer) --
// 128 blocks x 512 thr. Block: dir d = bid&1, jblk = bid>>1 -> 16 h-dims, all
// 4 gates. Wave w: gate mt = w>>1, K-half kh = w&1. Weights pinned in 64
// VGPRs/lane. h exchange: WRITE-ONCE trajectory buffer — sc1 write-through
// stores (+vmcnt(0) before barrier arrive), plain cached dwordx4 reads (each
// address written exactly once before any read; one agent acquire fence at
// kernel start invalidates lines cached by earlier dispatches). Grid barrier
// is PER-DIRECTION (64 blocks, 8x8 tree, relaxed agent atomics).
__global__ __launch_bounds__(PTHR) void lstm_persist(
    const u16* __restrict__ whh_r,  // [2d][2l][64 jblk][64 rows][1024] bf16
    const u16* __restrict__ xg,     // [2d][8192][4096] bf16
    u16*       __restrict__ htraj,  // [2d][8192][1024] bf16: slot tt = h(tt)
    float*     __restrict__ dout,
    unsigned*  __restrict__ cntb,   // zeroed; per-dir: +d*512; root 0, subs 16*(1+s)
    int layer)
{
  const int tid = threadIdx.x;
  const int lane = tid & 63;
  const int mt = (tid >> 6) >> 1, kh = (tid >> 6) & 1;
  const int d = blockIdx.x & 1, jblk = blockIdx.x >> 1;
  const int j0 = jblk * 16;
  const int fr = lane & 15, quad = lane >> 4;
  unsigned* cnt = cntb + (size_t)d * 512;

  __builtin_amdgcn_fence(__ATOMIC_ACQUIRE, "agent");   // drop stale L1/L2 lines (once)

  // 64 KB LDS: h staging [32 rows][128 chunks(16B)], phys chunk = c ^ (row&7)
  // (2-way-max bank aliasing = free, m136). First 16 KB reused as the gate-
  // partial exchange buffer lAcc[4][2][32][16] (barrier-separated).
  __shared__ __align__(16) uint32_t lH[32 * 512];
  float* lAcc = (float*)lH;

  // ---- one-time weight fragment load, pinned in VGPRs ----
  u4_t wreg[16];
  {
    const u16* wp = whh_r
        + ((size_t)(((d * 2 + layer) * 64 + jblk) * 64 + mt * 16 + fr)) * KD
        + kh * 512 + quad * 8;
    #pragma unroll
    for (int ks = 0; ks < 16; ks++) wreg[ks] = *(const u4_t*)(wp + ks * 32);
    #pragma unroll
    for (int ks = 0; ks < 16; ks++) asm volatile("" : "+v"(wreg[ks]));  // stop load sinking
  }

  const int b_ = tid >> 3, jp = tid & 7;   // cell phase: tid<256 -> (batch, j-pair)
  float cr0 = 0.0f, cr1 = 0.0f;

  for (int t = 0; t < SEQ; t++) {
    const int tt = d ? (SEQ - 1 - t) : t;

    uint32_t xv[4];                        // xg for this cell (cached loads)
    if (tid < 256) {
      const uint32_t* xgp = (const uint32_t*)(xg
          + ((size_t)d * MROWS + (size_t)tt * BSZ + b_) * GD + j0) + jp;
      #pragma unroll
      for (int g = 0; g < 4; g++) xv[g] = xgp[g * 512];
    }

    if (t > 0) {
      // ---- stage h(prev) from trajectory slot (plain cached 16B loads) ----
      const int ttp = d ? (tt + 1) : (tt - 1);
      const u16* hsrc = htraj + ((size_t)d * MROWS + (size_t)ttp * BSZ) * HD;
      u4_t hv[8];
      #pragma unroll
      for (int g = 0; g < 8; g++)
        hv[g] = *(const u4_t*)(hsrc + (size_t)(g * 512 + tid) * 8);
      #pragma unroll
      for (int g = 0; g < 8; g++) {
        int lc = g * 512 + tid;            // 16B-chunk index in [32][128]
        int row = lc >> 7, c = lc & 127;
        int pc = c ^ (row & 7);
        *(u4_t*)&lH[row * 512 + pc * 4] = hv[g];
      }
      __syncthreads();

      // ---- recurrent MFMA: gate mt, K-half kh ----
      f4_t acc0 = {}, acc1 = {};
      #pragma unroll
      for (int ks = 0; ks < 16; ks++) {
        int cbase = ((kh * 64 + ks * 4 + quad) ^ (fr & 7)) << 2;  // (fr+16)&7==fr&7
        bf8_t a0 = *(const bf8_t*)&lH[fr * 512 + cbase];          // batches 0-15
        bf8_t a1 = *(const bf8_t*)&lH[(fr + 16) * 512 + cbase];   // batches 16-31
        bf8_t wb = __builtin_bit_cast(bf8_t, wreg[ks]);
        acc0 = __builtin_amdgcn_mfma_f32_16x16x32_bf16(a0, wb, acc0, 0, 0, 0);
        acc1 = __builtin_amdgcn_mfma_f32_16x16x32_bf16(a1, wb, acc1, 0, 0, 0);
      }
      __syncthreads();                     // frag reads done: lAcc may overlay lH

      // D layout: col=lane&15 (j), row=(lane>>4)*4+r (batch)
      #pragma unroll
      for (int r = 0; r < 4; r++) {
        lAcc[((mt * 2 + kh) * 32 + quad * 4 + r) * 16 + fr]      = acc0[r];
        lAcc[((mt * 2 + kh) * 32 + 16 + quad * 4 + r) * 16 + fr] = acc1[r];
      }
      __syncthreads();
    }

    // ---- cell update: 256 threads x 2 adjacent j each ----
    if (tid < 256) {
      float vg0[4], vg1[4];
      #pragma unroll
      for (int g = 0; g < 4; g++) {
        float s0 = 0.f, s1 = 0.f;
        if (t > 0) {
          float2 p0 = *(const float2*)&lAcc[((g * 2 + 0) * 32 + b_) * 16 + 2 * jp];
          float2 p1 = *(const float2*)&lAcc[((g * 2 + 1) * 32 + b_) * 16 + 2 * jp];
          s0 = p0.x + p1.x; s1 = p0.y + p1.y;
        }
        vg0[g] = s0 + bf2f((u16)(xv[g] & 0xffffu));
        vg1[g] = s1 + bf2f((u16)(xv[g] >> 16));
      }
      float i0 = sigm(vg0[0]), f0 = sigm(vg0[1]), g0 = tanh_f(vg0[2]), o0 = sigm(vg0[3]);
      float i1 = sigm(vg1[0]), f1 = sigm(vg1[1]), g1 = tanh_f(vg1[2]), o1 = sigm(vg1[3]);
      cr0 = f0 * cr0 + i0 * g0;
      cr1 = f1 * cr1 + i1 * g1;
      float hn0 = o0 * tanh_f(cr0), hn1 = o1 * tanh_f(cr1);
      uint32_t hnp = ((uint32_t)f2bf(hn1) << 16) | (uint32_t)f2bf(hn0);

      // write-once trajectory store (device-coherent write-through)
      size_t hq = (((size_t)d * MROWS + (size_t)tt * BSZ + b_) * HD + j0 + 2 * jp) >> 1;
      __hip_atomic_store((uint32_t*)htraj + hq, hnp, __ATOMIC_RELAXED, __HIP_MEMORY_SCOPE_AGENT);

      if (layer == 1) {
        float2 o2 = make_float2(hn0, hn1);
        *(float2*)&dout[((size_t)tt * BSZ + b_) * (2 * HD) + (size_t)d * HD + j0 + 2 * jp] = o2;
      }
      // h_last/c_last: fwd at final step; bwd at its FIRST step (torch quirk)
      if ((d == 0 && t == SEQ - 1) || (d == 1 && t == 0)) {
        size_t hoff = (size_t)MROWS * 2 * HD + ((size_t)layer * BSZ + b_) * (2 * HD)
                    + (size_t)d * HD + j0 + 2 * jp;
        dout[hoff] = hn0;  dout[hoff + 1] = hn1;
        dout[hoff + (size_t)2 * BSZ * 2 * HD]     = cr0;
        dout[hoff + (size_t)2 * BSZ * 2 * HD + 1] = cr1;
      }
    }

    // ---- per-direction grid barrier (no cache-wide fences) ----
    asm volatile("s_waitcnt vmcnt(0)" ::: "memory");  // sc1 stores performed at MALL
    __syncthreads();
    if (tid == 0) {
      const unsigned sub = (unsigned)((blockIdx.x >> 1) & 7);
      unsigned old = __hip_atomic_fetch_add(&cnt[16 * (1 + sub)], 1u,
                                            __ATOMIC_RELAXED, __HIP_MEMORY_SCOPE_AGENT);
      if (old + 1u == 8u * (unsigned)(t + 1))
        __hip_atomic_fetch_add(&cnt[0], 1u, __ATOMIC_RELAXED, __HIP_MEMORY_SCOPE_AGENT);
      const unsigned goal = 8u * (unsigned)(t + 1);
      long spins = 0;
      while (__hip_atomic_load(&cnt[0], __ATOMIC_RELAXED, __HIP_MEMORY_SCOPE_AGENT) < goal) {
        if (++spins > (1L << 27)) break;   // safety escape (never under co-residency)
      }
    }
    __syncthreads();
    asm volatile("" ::: "memory");         // keep next step's loads below the barrier
  }
}

// -------------------------------------------------------------------------
extern "C" void kernel_launch(void* const* d_in, const int* in_sizes, int n_in,
                              void* d_out, int out_size, void* d_ws, size_t ws_size,
                              hipStream_t stream) {
  const float* x    = (const float*)d_in[0];
  const float* wihf = (const float*)d_in[1];
  const float* whhf = (const float*)d_in[2];
  const float* wihb = (const float*)d_in[3];
  const float* whhb = (const float*)d_in[4];
  float* out = (float*)d_out;

  const size_t NE = (size_t)MROWS * KD;   // 8.4M elems per [2,4096,1024] tensor
  char* ws = (char*)d_ws;
  u16*   xbf  = (u16*)ws;                                   // 16 MB
  u16*   wih  = (u16*)(ws + NE * 2);                        // 32 MB
  u16*   whhr = wih + 2 * NE;                               // reordered, 32 MB
  u16*   xg   = whhr + 2 * NE;                              // 128 MB
  u16*   h0   = xg + (size_t)2 * MROWS * GD;                // 32 MB (trajectory, both layers)
  unsigned* cnt = (unsigned*)(h0 + (size_t)2 * MROWS * HD); // 2 layers x 2 dirs x 2 KB

  const int n4 = (int)(NE / 4);
  const int cg = n4 / 256;
  cvt_f32_bf16<<<cg, 256, 0, stream>>>(x,    xbf,      n4);
  cvt_f32_bf16<<<cg, 256, 0, stream>>>(wihf, wih,      n4);
  cvt_f32_bf16<<<cg, 256, 0, stream>>>(wihb, wih + NE, n4);
  reorder_whh<<<2 * GD, 256, 0, stream>>>(whhf, whhr, 0);
  reorder_whh<<<2 * GD, 256, 0, stream>>>(whhb, whhr, 1);

  hipMemsetAsync(cnt, 0, 4 * 512 * sizeof(unsigned), stream);

  dim3 gg(MROWS / 128, GD / 128);   // 64 x 32

  // layer 0: xg GEMMs, then persistent recurrence (h trajectory -> h0)
  for (int d = 0; d < 2; d++)
    gemm_bt<<<gg, 256, 0, stream>>>(xbf, wih + (size_t)(d * 2) * GD * KD,
                                    xg + (size_t)d * MROWS * GD, MROWS, GD, KD);
  lstm_persist<<<PBLK, PTHR, 0, stream>>>(whhr, xg, h0, out, cnt, 0);

  // layer 1: xg GEMMs read h0, then recurrence overwrites h0 as its trajectory
  for (int d = 0; d < 2; d++)
    gemm_bt<<<gg, 256, 0, stream>>>(h0 + (size_t)d * MROWS * HD,
                                    wih + (size_t)(d * 2 + 1) * GD * KD,
                                    xg + (size_t)d * MROWS * GD, MROWS, GD, KD);
  lstm_persist<<<PBLK, PTHR, 0, stream>>>(whhr, xg, h0, out, cnt + 1024, 1);
}